// Round 1
// baseline (1714.078 us; speedup 1.0000x reference)
//
#include <hip/hip_runtime.h>
#include <hip/hip_bf16.h>

// Problem constants (fixed by reference):
// N=400000, H=256, C=128, A=32, G=512, NG=1024, BN_EPS=1e-5
#define NNODES 400000
#define BM 128           // nodes per block in K1 (400000/128 = 3125 exact)

typedef __attribute__((ext_vector_type(8))) short  short8;   // 8 x bf16 (4 VGPRs)
typedef __attribute__((ext_vector_type(4))) float  floatx4;  // 4 x f32 acc

typedef unsigned short u16;
typedef unsigned int   u32;

// fp32 -> bf16 round-to-nearest-even (inputs are finite gaussians; no NaN path)
__device__ __forceinline__ short f2bf(float f) {
    u32 u = __builtin_bit_cast(u32, f);
    u += 0x7fffu + ((u >> 16) & 1u);
    return (short)(u >> 16);
}

// async 16B/lane global->LDS copy; dst is wave-uniform base (HW adds lane*16)
__device__ __forceinline__ void async16(const void* g, void* l) {
    __builtin_amdgcn_global_load_lds(
        (const __attribute__((address_space(1))) u32*)g,
        (__attribute__((address_space(3))) u32*)l, 16, 0, 0);
}

// ---------------------------------------------------------------------------
// K0: build packed bf16 weights, zero-free two-section layout.
//   Gate section (64K u16):  idx = kc*4096 + quad*1024 + col*8 + j
//                            value = Wg[kc*32+quad*8+j][col],  kc 0..15
//   T section    (32K u16):  idx = 65536 + kct*4096 + quad*1024 + col*8 + j
//                            value = Wt[kct*32+quad*8+j][col], kct 0..7
// 16B contiguous per (tile,quad,col) -> ds_read_b128 B-frags; 1KB-contiguous
// chunks for wave-uniform global_load_lds staging.
// ---------------------------------------------------------------------------
__global__ __launch_bounds__(256) void k0_build(
    const float* __restrict__ Wg, const float* __restrict__ Wt,
    u16* __restrict__ Bp)
{
    int base = (blockIdx.x * 256 + threadIdx.x) * 4;   // 96 blocks -> 98304
    #pragma unroll
    for (int e = 0; e < 4; e++) {
        int idx   = base + e;
        int local = idx & 4095;
        int quad  = local >> 10;
        int col   = (local >> 3) & 127;
        int j     = local & 7;
        float v;
        if (idx < 65536) {
            int kc = idx >> 12;
            v = Wg[(kc * 32 + quad * 8 + j) * 128 + col];
        } else {
            int kct = (idx - 65536) >> 12;
            v = Wt[(kct * 32 + quad * 8 + j) * 128 + col];
        }
        Bp[idx] = (u16)f2bf(v);
    }
}

// ---------------------------------------------------------------------------
// K1: node GEMM (bf16 MFMA) + sigmoid-gate + register segment-sum.
// Block: 512 threads = 8 waves; wave w owns node rows [w*16, w*16+16).
// BM=128 with the same 33 KB LDS footprint -> 4 blocks/CU carry 32 waves/CU
// (100% occupancy) instead of 16; per-node barrier-drain count halves.
// Phase 1 (kc 0..7):  A = init rows, gate tiles only      (8 MFMA/iter)
// Phase 2 (kc 8..15): A = fin rows, gate + t tiles        (16 MFMA/iter)
// Double-buffered B staging, one barrier per iteration, A prefetched 1 iter
// ahead. Epilogue: sigmoid(g)*t in-lane, cross-quad shfl_xor reduction,
// 1 atomic per column per wave on the (~96%) gid-uniform fast path.
// __launch_bounds__(512, 8): pin VGPR <= 64 (body already fits 64 exactly).
// ---------------------------------------------------------------------------
__global__ __launch_bounds__(512, 8) void k1_gemm(
    const float* __restrict__ initS, const float* __restrict__ finS,
    const int* __restrict__ gids, const u16* __restrict__ Bp,
    const float* __restrict__ bg, const float* __restrict__ bt,
    float* __restrict__ readout)
{
    __shared__ __align__(16) u16 Bl[2][8192];   // 2 x 16 KB B tiles
    __shared__ int gidL[BM];

    const int tid  = threadIdx.x;
    const int w    = tid >> 6;        // wave 0..7
    const int lane = tid & 63;
    const int quad = lane >> 4;       // 0..3
    const int l15  = lane & 15;       // 0..15
    const int nodeBase = blockIdx.x * BM;

    if (tid < BM) gidL[tid] = gids[nodeBase + tid];

    floatx4 accg[8], acct[8];
    #pragma unroll
    for (int i = 0; i < 8; i++) {
        accg[i] = (floatx4){0.f, 0.f, 0.f, 0.f};
        acct[i] = (floatx4){0.f, 0.f, 0.f, 0.f};
    }

    const int rowNode = nodeBase + w * 16 + l15;   // A row this lane feeds
    const float* initRow = initS + (size_t)rowNode * 256;
    const float* finRow  = finS  + (size_t)rowNode * 256;

    // --- stage helper: gate tile = chunks 0..7, t = 8..15 (1 KB chunks) ---
    auto stage = [&](int kc, u16* lbuf) {
        if (kc < 8) {                       // 8 KB: gate only, 1 chunk/wave
            async16(Bp + (size_t)kc * 4096 + w * 512 + lane * 8, lbuf + w * 512);
        } else {                            // 16 KB: gate + t, 2 chunks/wave
            #pragma unroll
            for (int i = 0; i < 2; i++) {
                int c = w * 2 + i;
                const u16* src = (c < 8)
                    ? (Bp + (size_t)kc * 4096 + c * 512)
                    : (Bp + 65536 + (size_t)(kc - 8) * 4096 + (c - 8) * 512);
                async16(src + lane * 8, lbuf + c * 512);
            }
        }
    };

    // prologue: stage tile 0, load A(0)
    stage(0, Bl[0]);
    const float* ar = initRow + quad * 8;
    float4 a0 = *reinterpret_cast<const float4*>(ar);
    float4 a1 = *reinterpret_cast<const float4*>(ar + 4);

    for (int kc = 0; kc < 16; kc++) {
        const u16* cur = Bl[kc & 1];
        __syncthreads();   // publishes B(kc) staging + A(kc) prefetch (vmcnt drain)

        float4 a0n, a1n;
        if (kc < 15) {
            stage(kc + 1, Bl[(kc + 1) & 1]);           // in flight across MFMAs
            const float* arn = ((kc + 1) < 8)
                ? (initRow + (kc + 1) * 32 + quad * 8)
                : (finRow + (kc + 1 - 8) * 32 + quad * 8);
            a0n = *reinterpret_cast<const float4*>(arn);
            a1n = *reinterpret_cast<const float4*>(arn + 4);
        }

        short8 af;
        af[0] = f2bf(a0.x); af[1] = f2bf(a0.y); af[2] = f2bf(a0.z); af[3] = f2bf(a0.w);
        af[4] = f2bf(a1.x); af[5] = f2bf(a1.y); af[6] = f2bf(a1.z); af[7] = f2bf(a1.w);

        #pragma unroll
        for (int ct = 0; ct < 8; ct++) {
            short8 bf = *reinterpret_cast<const short8*>(
                cur + quad * 1024 + (ct * 16 + l15) * 8);
            accg[ct] = __builtin_amdgcn_mfma_f32_16x16x32_bf16(af, bf, accg[ct], 0, 0, 0);
        }
        if (kc >= 8) {
            #pragma unroll
            for (int ct = 0; ct < 8; ct++) {
                short8 bf = *reinterpret_cast<const short8*>(
                    cur + 4096 + quad * 1024 + (ct * 16 + l15) * 8);
                acct[ct] = __builtin_amdgcn_mfma_f32_16x16x32_bf16(af, bf, acct[ct], 0, 0, 0);
            }
        }
        a0 = a0n; a1 = a1n;
    }

    // ---- epilogue: fuse + segment-sum from registers ----
    // C/D layout: col = ct*16 + l15, row (within wave tile) = quad*4 + reg.
    const int rbase = w * 16;
    const int gFirst = gidL[rbase];
    const int gLast  = gidL[rbase + 15];

    if (gFirst == gLast) {
        // fast path: whole 16-row wave tile in one graph
        #pragma unroll
        for (int ct = 0; ct < 8; ct++) {
            const float bgv = bg[ct * 16 + l15];
            const float btv = bt[ct * 16 + l15];
            float s = 0.f;
            #pragma unroll
            for (int i = 0; i < 4; i++) {
                float g = accg[ct][i] + bgv;
                float t = acct[ct][i] + btv;
                s += t / (1.0f + __expf(-g));
            }
            s += __shfl_xor(s, 16);   // sum across quads (rows)
            s += __shfl_xor(s, 32);
            if ((ct >> 1) == quad)    // 1 atomic per column per wave
                atomicAdd(&readout[gFirst * 128 + ct * 16 + l15], s);
        }
    } else {
        // slow path (~4% of waves): per-lane sorted-run flush over its 4 rows
        float s[8];
        #pragma unroll
        for (int ct = 0; ct < 8; ct++) s[ct] = 0.f;
        int curg = gidL[rbase + quad * 4];
        #pragma unroll
        for (int i = 0; i < 4; i++) {
            int g = gidL[rbase + quad * 4 + i];
            if (g != curg) {
                #pragma unroll
                for (int ct = 0; ct < 8; ct++) {
                    atomicAdd(&readout[curg * 128 + ct * 16 + l15], s[ct]);
                    s[ct] = 0.f;
                }
                curg = g;
            }
            #pragma unroll
            for (int ct = 0; ct < 8; ct++) {
                float gg = accg[ct][i] + bg[ct * 16 + l15];
                float tt = acct[ct][i] + bt[ct * 16 + l15];
                s[ct] += tt / (1.0f + __expf(-gg));
            }
        }
        #pragma unroll
        for (int ct = 0; ct < 8; ct++)
            atomicAdd(&readout[curg * 128 + ct * 16 + l15], s[ct]);
    }
}

// ---------------------------------------------------------------------------
// K2: BatchNorm column stats over the 1024-row batch (biased variance),
// folded into scale/shift: y = x*scale[c] + shift[c].
// ---------------------------------------------------------------------------
__global__ __launch_bounds__(256) void k2_stats(
    const float* __restrict__ readout, const float* __restrict__ aux,
    const float* __restrict__ gamma, const float* __restrict__ beta,
    float* __restrict__ scale, float* __restrict__ shift)
{
    const int col = blockIdx.x;     // 0..159
    const int tid = threadIdx.x;
    float s = 0.f, q = 0.f;
    for (int g = tid; g < 1024; g += 256) {
        float v = (col < 128) ? readout[g * 128 + col] : aux[g * 32 + (col - 128)];
        s += v; q += v * v;
    }
    #pragma unroll
    for (int off = 32; off > 0; off >>= 1) {
        s += __shfl_down(s, off);
        q += __shfl_down(q, off);
    }
    __shared__ float ps[4], pq[4];
    if ((tid & 63) == 0) { ps[tid >> 6] = s; pq[tid >> 6] = q; }
    __syncthreads();
    if (tid == 0) {
        float S = ps[0] + ps[1] + ps[2] + ps[3];
        float Q = pq[0] + pq[1] + pq[2] + pq[3];
        float mean = S * (1.0f / 1024.0f);
        float var  = Q * (1.0f / 1024.0f) - mean * mean;
        float rstd = rsqrtf(var + 1e-5f);
        float sc   = gamma[col] * rstd;
        scale[col] = sc;
        shift[col] = beta[col] - mean * sc;
    }
}

// ---------------------------------------------------------------------------
// K3a: hidden = relu(norm @ W1 + b1), BN fold applied inside the k-loop so the
// activations are RAW global rows (wave-uniform addresses -> scalar loads).
// ---------------------------------------------------------------------------
__global__ __launch_bounds__(256) void k3a_hidden(
    const float* __restrict__ readout, const float* __restrict__ aux,
    const float* __restrict__ scale, const float* __restrict__ shift,
    const float* __restrict__ W1, const float* __restrict__ b1,
    float* __restrict__ hidden)
{
    const int g0  = blockIdx.x * 4;   // 256 blocks
    const int tid = threadIdx.x;
    const float* r0 = readout + (size_t)g0 * 128;
    const float* a0 = aux     + (size_t)g0 * 32;

    #pragma unroll
    for (int jj = 0; jj < 2; jj++) {
        const int j = tid + jj * 256;
        float acc0 = 0.f, acc1 = 0.f, acc2 = 0.f, acc3 = 0.f, accS = 0.f;
        for (int k = 0; k < 128; k++) {
            float wv = W1[k * 512 + j];
            accS += shift[k] * wv;
            float wsv = scale[k] * wv;
            acc0 += r0[k]       * wsv;
            acc1 += r0[128 + k] * wsv;
            acc2 += r0[256 + k] * wsv;
            acc3 += r0[384 + k] * wsv;
        }
        for (int k = 0; k < 32; k++) {
            float wv = W1[(128 + k) * 512 + j];
            accS += shift[128 + k] * wv;
            float wsv = scale[128 + k] * wv;
            acc0 += a0[k]      * wsv;
            acc1 += a0[32 + k] * wsv;
            acc2 += a0[64 + k] * wsv;
            acc3 += a0[96 + k] * wsv;
        }
        float bb = b1[j] + accS;
        hidden[(size_t)(g0 + 0) * 512 + j] = fmaxf(acc0 + bb, 0.f);
        hidden[(size_t)(g0 + 1) * 512 + j] = fmaxf(acc1 + bb, 0.f);
        hidden[(size_t)(g0 + 2) * 512 + j] = fmaxf(acc2 + bb, 0.f);
        hidden[(size_t)(g0 + 3) * 512 + j] = fmaxf(acc3 + bb, 0.f);
    }
}

// ---------------------------------------------------------------------------
// K3b: logits = hidden @ W2 + b2. Same uniform-broadcast trick on hidden rows.
// ---------------------------------------------------------------------------
__global__ __launch_bounds__(256) void k3b_logits(
    const float* __restrict__ hidden, const float* __restrict__ W2,
    const float* __restrict__ b2, float* __restrict__ out)
{
    const int g0  = blockIdx.x * 4;   // 256 blocks
    const int tid = threadIdx.x;
    const int j   = tid & 127;
    const int rh  = tid >> 7;         // rows rh*2, rh*2+1
    const float* h0 = hidden + (size_t)(g0 + rh * 2) * 512;
    float acc0 = 0.f, acc1 = 0.f;
    for (int k = 0; k < 512; k++) {
        float wv = W2[k * 128 + j];
        acc0 += h0[k]       * wv;
        acc1 += h0[512 + k] * wv;
    }
    float bb = b2[j];
    out[(size_t)(g0 + rh * 2 + 0) * 128 + j] = acc0 + bb;
    out[(size_t)(g0 + rh * 2 + 1) * 128 + j] = acc1 + bb;
}

// ---------------------------------------------------------------------------
extern "C" void kernel_launch(void* const* d_in, const int* in_sizes, int n_in,
                              void* d_out, int out_size, void* d_ws, size_t ws_size,
                              hipStream_t stream)
{
    const float* initS = (const float*)d_in[0];   // [400000,256]
    const float* finS  = (const float*)d_in[1];   // [400000,256]
    const float* aux   = (const float*)d_in[2];   // [1024,32]
    const int*   gid   = (const int*)d_in[3];     // [400000] sorted
    // d_in[4] = num_graphs scalar (1024), unused
    const float* Wg    = (const float*)d_in[5];   // [512,128]
    const float* bg    = (const float*)d_in[6];   // [128]
    const float* Wt    = (const float*)d_in[7];   // [256,128]
    const float* bt    = (const float*)d_in[8];   // [128]
    const float* gamma = (const float*)d_in[9];   // [160]
    const float* beta  = (const float*)d_in[10];  // [160]
    const float* W1    = (const float*)d_in[11];  // [160,512]
    const float* b1    = (const float*)d_in[12];  // [512]
    const float* W2    = (const float*)d_in[13];  // [512,128]
    const float* b2    = (const float*)d_in[14];  // [128]
    float* out = (float*)d_out;                   // [1024,128]

    char* ws = (char*)d_ws;
    u16*   Bp      = (u16*)(ws + 0);              // 192 KB packed bf16 weights
    float* readout = (float*)(ws + 262144);       // 512 KB  [1024,128]
    float* scale   = (float*)(ws + 786432);       // 640 B
    float* shift   = (float*)(ws + 787456);       // 640 B
    float* hidden  = (float*)(ws + 1048576);      // 2 MB    [1024,512]

    k0_build  <<<96, 256, 0, stream>>>(Wg, Wt, Bp);
    hipMemsetAsync(readout, 0, 1024 * 128 * sizeof(float), stream);
    k1_gemm   <<<NNODES / BM, 512, 0, stream>>>(initS, finS, gid, Bp, bg, bt, readout);
    k2_stats  <<<160, 256, 0, stream>>>(readout, aux, gamma, beta, scale, shift);
    k3a_hidden<<<256, 256, 0, stream>>>(readout, aux, scale, shift, W1, b1, hidden);
    k3b_logits<<<256, 256, 0, stream>>>(hidden, W2, b2, out);
}

// Round 2
// 1012.507 us; speedup vs baseline: 1.6929x; 1.6929x over previous
//
#include <hip/hip_runtime.h>
#include <hip/hip_bf16.h>

// Problem constants (fixed by reference):
// N=400000, H=256, C=128, A=32, G=512, NG=1024, BN_EPS=1e-5
#define NNODES 400000
#define BM 64            // nodes per block in K1 (400000/64 = 6250 exact)

typedef __attribute__((ext_vector_type(8))) short  short8;   // 8 x bf16 (4 VGPRs)
typedef __attribute__((ext_vector_type(4))) float  floatx4;  // 4 x f32 acc

typedef unsigned short u16;
typedef unsigned int   u32;

// fp32 -> bf16 round-to-nearest-even (inputs are finite gaussians; no NaN path)
__device__ __forceinline__ short f2bf(float f) {
    u32 u = __builtin_bit_cast(u32, f);
    u += 0x7fffu + ((u >> 16) & 1u);
    return (short)(u >> 16);
}

// ---------------------------------------------------------------------------
// K0: build packed bf16 weights, zero-free two-section layout.
//   Gate section (64K u16):  idx = kc*4096 + quad*1024 + col*8 + j
//                            value = Wg[kc*32+quad*8+j][col],  kc 0..15
//   T section    (32K u16):  idx = 65536 + kct*4096 + quad*1024 + col*8 + j
//                            value = Wt[kct*32+quad*8+j][col], kct 0..7
// 16B contiguous per (tile,quad,col) -> dwordx4 B-fragment loads in K1.
// ---------------------------------------------------------------------------
__global__ __launch_bounds__(256) void k0_build(
    const float* __restrict__ Wg, const float* __restrict__ Wt,
    u16* __restrict__ Bp)
{
    int base = (blockIdx.x * 256 + threadIdx.x) * 4;   // 96 blocks -> 98304
    #pragma unroll
    for (int e = 0; e < 4; e++) {
        int idx   = base + e;
        int local = idx & 4095;
        int quad  = local >> 10;
        int col   = (local >> 3) & 127;
        int j     = local & 7;
        float v;
        if (idx < 65536) {
            int kc = idx >> 12;
            v = Wg[(kc * 32 + quad * 8 + j) * 128 + col];
        } else {
            int kct = (idx - 65536) >> 12;
            v = Wt[(kct * 32 + quad * 8 + j) * 128 + col];
        }
        Bp[idx] = (u16)f2bf(v);
    }
}

// ---------------------------------------------------------------------------
// K1: node GEMM (bf16 MFMA) + sigmoid-gate + register segment-sum.
// BARRIER-FREE STRUCTURE (round 2): no LDS, no __syncthreads.
//   - B fragments are read straight from global Bp (192 KB, L2-resident;
//     8-16 KB per kc -> L1-resident). Same per-lane address math as the old
//     LDS layout, so MFMA operand roles are unchanged.
//   - A raw s_barrier (no waitcnt semantics; nothing is shared) rate-matches
//     the block's 4 waves so they share L1 on B. A block's 4 waves sit on 4
//     different SIMDs; each SIMD hosts waves of 4 *different* blocks, which
//     stay unsynchronized -> TLP hides the A-load latency that the old
//     __syncthreads (vmcnt(0) drain) exposed every iteration.
//   - Register budget: 64 f32 accumulator (AGPR) + <=64 VGPR working set
//     -> 128 unified regs/wave -> 16 waves/CU. Do NOT tighten launch_bounds
//     further: round 1 showed (512,8) forces 64 total regs and spills the
//     accumulator to scratch (WRITE_SIZE 15 MB -> 2.4 GB, 4x slower).
// Phase 1 (kc 0..7):  A = init rows, gate tiles only      (8 MFMA/iter)
// Phase 2 (kc 8..15): A = fin rows, gate + t tiles        (16 MFMA/iter)
// Epilogue: sigmoid(g)*t in-lane, cross-quad shfl_xor reduction,
// 1 atomic per column per wave on the (~96%) gid-uniform fast path.
// ---------------------------------------------------------------------------
__global__ __launch_bounds__(256, 4) void k1_gemm(
    const float* __restrict__ initS, const float* __restrict__ finS,
    const int* __restrict__ gids, const u16* __restrict__ Bp,
    const float* __restrict__ bg, const float* __restrict__ bt,
    float* __restrict__ readout)
{
    const int tid  = threadIdx.x;
    const int w    = tid >> 6;        // wave 0..3
    const int lane = tid & 63;
    const int quad = lane >> 4;       // 0..3
    const int l15  = lane & 15;       // 0..15
    const int nodeBase = blockIdx.x * BM;

    const int rowNode = nodeBase + w * 16 + l15;   // A row this lane feeds
    const int myg = gids[rowNode];                 // lane j (j<16 rep) = gid of row j

    floatx4 accg[8], acct[8];
    #pragma unroll
    for (int i = 0; i < 8; i++) {
        accg[i] = (floatx4){0.f, 0.f, 0.f, 0.f};
        acct[i] = (floatx4){0.f, 0.f, 0.f, 0.f};
    }

    const float* initRow = initS + (size_t)rowNode * 256;
    const float* finRow  = finS  + (size_t)rowNode * 256;

    // lane-fixed byte offsets into a 4096-element (8 KB) kc tile
    const u16* BgBase = Bp + quad * 1024 + l15 * 8;           // gate section
    const u16* BtBase = Bp + 65536 + quad * 1024 + l15 * 8;   // t section

    // A(0) prefetch
    const float* ar = initRow + quad * 8;
    float4 a0 = *reinterpret_cast<const float4*>(ar);
    float4 a1 = *reinterpret_cast<const float4*>(ar + 4);

    for (int kc = 0; kc < 16; kc++) {
        __builtin_amdgcn_s_barrier();   // rate-match block's waves (L1 B-sharing only)

        float4 a0n, a1n;
        if (kc < 15) {
            const float* arn = ((kc + 1) < 8)
                ? (initRow + (kc + 1) * 32 + quad * 8)
                : (finRow + (kc + 1 - 8) * 32 + quad * 8);
            a0n = *reinterpret_cast<const float4*>(arn);
            a1n = *reinterpret_cast<const float4*>(arn + 4);
        }

        short8 af;
        af[0] = f2bf(a0.x); af[1] = f2bf(a0.y); af[2] = f2bf(a0.z); af[3] = f2bf(a0.w);
        af[4] = f2bf(a1.x); af[5] = f2bf(a1.y); af[6] = f2bf(a1.z); af[7] = f2bf(a1.w);

        const u16* bgp = BgBase + (size_t)kc * 4096;
        #pragma unroll
        for (int ct = 0; ct < 8; ct++) {
            short8 bf = *reinterpret_cast<const short8*>(bgp + ct * 128);
            accg[ct] = __builtin_amdgcn_mfma_f32_16x16x32_bf16(af, bf, accg[ct], 0, 0, 0);
        }
        if (kc >= 8) {
            const u16* btp = BtBase + (size_t)(kc - 8) * 4096;
            #pragma unroll
            for (int ct = 0; ct < 8; ct++) {
                short8 bf = *reinterpret_cast<const short8*>(btp + ct * 128);
                acct[ct] = __builtin_amdgcn_mfma_f32_16x16x32_bf16(af, bf, acct[ct], 0, 0, 0);
            }
        }
        a0 = a0n; a1 = a1n;
    }

    // ---- epilogue: fuse + segment-sum from registers ----
    // C/D layout: col = ct*16 + l15, row (within wave tile) = quad*4 + reg.
    const int gFirst = __shfl(myg, 0);    // lane 0 holds row 0
    const int gLast  = __shfl(myg, 15);   // lane 15 holds row 15

    if (gFirst == gLast) {
        // fast path: whole 16-row wave tile in one graph
        #pragma unroll
        for (int ct = 0; ct < 8; ct++) {
            const float bgv = bg[ct * 16 + l15];
            const float btv = bt[ct * 16 + l15];
            float s = 0.f;
            #pragma unroll
            for (int i = 0; i < 4; i++) {
                float g = accg[ct][i] + bgv;
                float t = acct[ct][i] + btv;
                s += t / (1.0f + __expf(-g));
            }
            s += __shfl_xor(s, 16);   // sum across quads (rows)
            s += __shfl_xor(s, 32);
            if ((ct >> 1) == quad)    // 1 atomic per column per wave
                atomicAdd(&readout[gFirst * 128 + ct * 16 + l15], s);
        }
    } else {
        // slow path (~4% of waves): per-lane sorted-run flush over its 4 rows
        float s[8];
        #pragma unroll
        for (int ct = 0; ct < 8; ct++) s[ct] = 0.f;
        int curg = __shfl(myg, quad * 4);
        #pragma unroll
        for (int i = 0; i < 4; i++) {
            int g = __shfl(myg, quad * 4 + i);
            if (g != curg) {
                #pragma unroll
                for (int ct = 0; ct < 8; ct++) {
                    atomicAdd(&readout[curg * 128 + ct * 16 + l15], s[ct]);
                    s[ct] = 0.f;
                }
                curg = g;
            }
            #pragma unroll
            for (int ct = 0; ct < 8; ct++) {
                float gg = accg[ct][i] + bg[ct * 16 + l15];
                float tt = acct[ct][i] + bt[ct * 16 + l15];
                s[ct] += tt / (1.0f + __expf(-gg));
            }
        }
        #pragma unroll
        for (int ct = 0; ct < 8; ct++)
            atomicAdd(&readout[curg * 128 + ct * 16 + l15], s[ct]);
    }
}

// ---------------------------------------------------------------------------
// K2: BatchNorm column stats over the 1024-row batch (biased variance),
// folded into scale/shift: y = x*scale[c] + shift[c].
// ---------------------------------------------------------------------------
__global__ __launch_bounds__(256) void k2_stats(
    const float* __restrict__ readout, const float* __restrict__ aux,
    const float* __restrict__ gamma, const float* __restrict__ beta,
    float* __restrict__ scale, float* __restrict__ shift)
{
    const int col = blockIdx.x;     // 0..159
    const int tid = threadIdx.x;
    float s = 0.f, q = 0.f;
    for (int g = tid; g < 1024; g += 256) {
        float v = (col < 128) ? readout[g * 128 + col] : aux[g * 32 + (col - 128)];
        s += v; q += v * v;
    }
    #pragma unroll
    for (int off = 32; off > 0; off >>= 1) {
        s += __shfl_down(s, off);
        q += __shfl_down(q, off);
    }
    __shared__ float ps[4], pq[4];
    if ((tid & 63) == 0) { ps[tid >> 6] = s; pq[tid >> 6] = q; }
    __syncthreads();
    if (tid == 0) {
        float S = ps[0] + ps[1] + ps[2] + ps[3];
        float Q = pq[0] + pq[1] + pq[2] + pq[3];
        float mean = S * (1.0f / 1024.0f);
        float var  = Q * (1.0f / 1024.0f) - mean * mean;
        float rstd = rsqrtf(var + 1e-5f);
        float sc   = gamma[col] * rstd;
        scale[col] = sc;
        shift[col] = beta[col] - mean * sc;
    }
}

// ---------------------------------------------------------------------------
// K3a: hidden = relu(norm @ W1 + b1), BN fold applied inside the k-loop so the
// activations are RAW global rows (wave-uniform addresses -> scalar loads).
// ---------------------------------------------------------------------------
__global__ __launch_bounds__(256) void k3a_hidden(
    const float* __restrict__ readout, const float* __restrict__ aux,
    const float* __restrict__ scale, const float* __restrict__ shift,
    const float* __restrict__ W1, const float* __restrict__ b1,
    float* __restrict__ hidden)
{
    const int g0  = blockIdx.x * 4;   // 256 blocks
    const int tid = threadIdx.x;
    const float* r0 = readout + (size_t)g0 * 128;
    const float* a0 = aux     + (size_t)g0 * 32;

    #pragma unroll
    for (int jj = 0; jj < 2; jj++) {
        const int j = tid + jj * 256;
        float acc0 = 0.f, acc1 = 0.f, acc2 = 0.f, acc3 = 0.f, accS = 0.f;
        for (int k = 0; k < 128; k++) {
            float wv = W1[k * 512 + j];
            accS += shift[k] * wv;
            float wsv = scale[k] * wv;
            acc0 += r0[k]       * wsv;
            acc1 += r0[128 + k] * wsv;
            acc2 += r0[256 + k] * wsv;
            acc3 += r0[384 + k] * wsv;
        }
        for (int k = 0; k < 32; k++) {
            float wv = W1[(128 + k) * 512 + j];
            accS += shift[128 + k] * wv;
            float wsv = scale[128 + k] * wv;
            acc0 += a0[k]      * wsv;
            acc1 += a0[32 + k] * wsv;
            acc2 += a0[64 + k] * wsv;
            acc3 += a0[96 + k] * wsv;
        }
        float bb = b1[j] + accS;
        hidden[(size_t)(g0 + 0) * 512 + j] = fmaxf(acc0 + bb, 0.f);
        hidden[(size_t)(g0 + 1) * 512 + j] = fmaxf(acc1 + bb, 0.f);
        hidden[(size_t)(g0 + 2) * 512 + j] = fmaxf(acc2 + bb, 0.f);
        hidden[(size_t)(g0 + 3) * 512 + j] = fmaxf(acc3 + bb, 0.f);
    }
}

// ---------------------------------------------------------------------------
// K3b: logits = hidden @ W2 + b2. Same uniform-broadcast trick on hidden rows.
// ---------------------------------------------------------------------------
__global__ __launch_bounds__(256) void k3b_logits(
    const float* __restrict__ hidden, const float* __restrict__ W2,
    const float* __restrict__ b2, float* __restrict__ out)
{
    const int g0  = blockIdx.x * 4;   // 256 blocks
    const int tid = threadIdx.x;
    const int j   = tid & 127;
    const int rh  = tid >> 7;         // rows rh*2, rh*2+1
    const float* h0 = hidden + (size_t)(g0 + rh * 2) * 512;
    float acc0 = 0.f, acc1 = 0.f;
    for (int k = 0; k < 512; k++) {
        float wv = W2[k * 128 + j];
        acc0 += h0[k]       * wv;
        acc1 += h0[512 + k] * wv;
    }
    float bb = b2[j];
    out[(size_t)(g0 + rh * 2 + 0) * 128 + j] = acc0 + bb;
    out[(size_t)(g0 + rh * 2 + 1) * 128 + j] = acc1 + bb;
}

// ---------------------------------------------------------------------------
extern "C" void kernel_launch(void* const* d_in, const int* in_sizes, int n_in,
                              void* d_out, int out_size, void* d_ws, size_t ws_size,
                              hipStream_t stream)
{
    const float* initS = (const float*)d_in[0];   // [400000,256]
    const float* finS  = (const float*)d_in[1];   // [400000,256]
    const float* aux   = (const float*)d_in[2];   // [1024,32]
    const int*   gid   = (const int*)d_in[3];     // [400000] sorted
    // d_in[4] = num_graphs scalar (1024), unused
    const float* Wg    = (const float*)d_in[5];   // [512,128]
    const float* bg    = (const float*)d_in[6];   // [128]
    const float* Wt    = (const float*)d_in[7];   // [256,128]
    const float* bt    = (const float*)d_in[8];   // [128]
    const float* gamma = (const float*)d_in[9];   // [160]
    const float* beta  = (const float*)d_in[10];  // [160]
    const float* W1    = (const float*)d_in[11];  // [160,512]
    const float* b1    = (const float*)d_in[12];  // [512]
    const float* W2    = (const float*)d_in[13];  // [512,128]
    const float* b2    = (const float*)d_in[14];  // [128]
    float* out = (float*)d_out;                   // [1024,128]

    char* ws = (char*)d_ws;
    u16*   Bp      = (u16*)(ws + 0);              // 192 KB packed bf16 weights
    float* readout = (float*)(ws + 262144);       // 512 KB  [1024,128]
    float* scale   = (float*)(ws + 786432);       // 640 B
    float* shift   = (float*)(ws + 787456);       // 640 B
    float* hidden  = (float*)(ws + 1048576);      // 2 MB    [1024,512]

    k0_build  <<<96, 256, 0, stream>>>(Wg, Wt, Bp);
    hipMemsetAsync(readout, 0, 1024 * 128 * sizeof(float), stream);
    k1_gemm   <<<NNODES / BM, 256, 0, stream>>>(initS, finS, gid, Bp, bg, bt, readout);
    k2_stats  <<<160, 256, 0, stream>>>(readout, aux, gamma, beta, scale, shift);
    k3a_hidden<<<256, 256, 0, stream>>>(readout, aux, scale, shift, W1, b1, hidden);
    k3b_logits<<<256, 256, 0, stream>>>(hidden, W2, b2, out);
}

// Round 3
// 938.501 us; speedup vs baseline: 1.8264x; 1.0789x over previous
//
#include <hip/hip_runtime.h>
#include <hip/hip_bf16.h>

// Problem constants (fixed by reference):
// N=400000, H=256, C=128, A=32, G=512, NG=1024, BN_EPS=1e-5
#define NNODES 400000
#define BM 32            // nodes per block in K1 (400000/32 = 12500 exact)

typedef __attribute__((ext_vector_type(8))) short  short8;   // 8 x bf16 (4 VGPRs)
typedef __attribute__((ext_vector_type(4))) float  floatx4;  // 4 x f32 acc

typedef unsigned short u16;
typedef unsigned int   u32;

// fp32 -> bf16 round-to-nearest-even (inputs are finite gaussians; no NaN path)
__device__ __forceinline__ short f2bf(float f) {
    u32 u = __builtin_bit_cast(u32, f);
    u += 0x7fffu + ((u >> 16) & 1u);
    return (short)(u >> 16);
}

// async 16B/lane global->LDS copy; dst is wave-uniform base (HW adds lane*16)
__device__ __forceinline__ void async16(const void* g, void* l) {
    __builtin_amdgcn_global_load_lds(
        (const __attribute__((address_space(1))) u32*)g,
        (__attribute__((address_space(3))) u32*)l, 16, 0, 0);
}

// ---------------------------------------------------------------------------
// K0: build packed bf16 weights, zero-free two-section layout.
//   Gate section (64K u16):  idx = kc*4096 + quad*1024 + col*8 + j
//                            value = Wg[kc*32+quad*8+j][col],  kc 0..15
//   T section    (32K u16):  idx = 65536 + kct*4096 + quad*1024 + col*8 + j
//                            value = Wt[kct*32+quad*8+j][col], kct 0..7
// 16B contiguous per (tile,quad,col) -> dwordx4 B-fragment loads in K1.
// ---------------------------------------------------------------------------
__global__ __launch_bounds__(256) void k0_build(
    const float* __restrict__ Wg, const float* __restrict__ Wt,
    u16* __restrict__ Bp)
{
    int base = (blockIdx.x * 256 + threadIdx.x) * 4;   // 96 blocks -> 98304
    #pragma unroll
    for (int e = 0; e < 4; e++) {
        int idx   = base + e;
        int local = idx & 4095;
        int quad  = local >> 10;
        int col   = (local >> 3) & 127;
        int j     = local & 7;
        float v;
        if (idx < 65536) {
            int kc = idx >> 12;
            v = Wg[(kc * 32 + quad * 8 + j) * 128 + col];
        } else {
            int kct = (idx - 65536) >> 12;
            v = Wt[(kct * 32 + quad * 8 + j) * 128 + col];
        }
        Bp[idx] = (u16)f2bf(v);
    }
}

// ---------------------------------------------------------------------------
// K1 (round 3): PHASE-STAGED A, barrier-free kc loop.
// Diagnosis: round-0/2 read A in 128B chunks @1KB stride (each row touched 16x)
// -> ~46% DRAM efficiency; kernel is HBM-bound, so fix the access granularity.
// Structure:
//   - BM=32 nodes, 256 thr / 4 waves. Wave w = (node-half r=w>>1, col-half
//     c=w&1): 16 nodes x (64 gate + 64 t cols) -> acc = 32 regs (was 64).
//   - A staged PHASE-WISE into LDS: phase 1 uses ALL 256 init cols, phase 2
//     ALL 256 fin cols -> each stage = 32 full contiguous rows = one 32KB
//     contiguous HBM span (DRAM-optimal). 8 x global_load_lds(16B) per wave.
//   - A-LDS XOR swizzle: 16B unit u of row lr stored at u^(lr&7). Applied on
//     the STAGE SOURCE address and the READ address (involution, both-sides).
//     Breaks the 16-lanes-same-bank column read (rows stride 1KB = 0 mod 32).
//   - B read per-lane straight from Bp (192KB, L2-resident; tile L1-shared).
//   - NO per-kc barrier: only 3 __syncthreads per block (A publish / WAR /
//     fin publish). Waves free-run -> requests flow continuously.
//   - LDS = 32KB exact; launch_bounds(256,4) caps 128 unified regs (round-1
//     lesson: never force below the 32-reg accumulator + working set).
// ---------------------------------------------------------------------------
__global__ __launch_bounds__(256, 4) void k1_gemm(
    const float* __restrict__ initS, const float* __restrict__ finS,
    const int* __restrict__ gids, const u16* __restrict__ Bp,
    const float* __restrict__ bg, const float* __restrict__ bt,
    float* __restrict__ readout)
{
    __shared__ __align__(16) float Abuf[BM][256];   // 32 KB

    const int tid  = threadIdx.x;
    const int w    = tid >> 6;        // wave 0..3
    const int lane = tid & 63;
    const int quad = lane >> 4;       // 0..3
    const int l15  = lane & 15;       // 0..15
    const int r    = w >> 1;          // node-half 0/1
    const int c    = w & 1;           // col-half 0/1
    const int nodeBase = blockIdx.x * BM;

    const int lr = r * 16 + l15;      // local A row this lane's frag comes from
    const int m  = l15 & 7;           // swizzle mask (== lr & 7)

    const int myg = gids[nodeBase + lr];   // gid of row lr (lanes repeat per l15)

    floatx4 accg[4], acct[4];
    #pragma unroll
    for (int i = 0; i < 4; i++) {
        accg[i] = (floatx4){0.f, 0.f, 0.f, 0.f};
        acct[i] = (floatx4){0.f, 0.f, 0.f, 0.f};
    }

    // ---- stage A(init): wave w stages local rows w*8..w*8+8, each row is one
    //      1KB global_load_lds; source lane-addr pre-swizzled (unit ^= row&7).
    {
        const float* src = initS + (size_t)(nodeBase + w * 8) * 256;
        #pragma unroll
        for (int i = 0; i < 8; i++)
            async16(src + i * 256 + ((lane ^ i) << 2), &Abuf[w * 8 + i][0]);
    }
    __syncthreads();   // vmcnt(0) drain publishes A(init)

    // lane-fixed B bases for this wave's col-half (u16 elements)
    const u16* BgL = Bp + quad * 1024 + c * 512 + l15 * 8;           // gate
    const u16* BtL = BgL + 65536;                                    // t

    // ---- phase 1: gate += init @ Wg[0:256], kc 0..7, 4 MFMA/iter ----
    #pragma unroll 2
    for (int kc = 0; kc < 8; kc++) {
        const float4 x0 = *reinterpret_cast<const float4*>(
            &Abuf[lr][(kc * 8 + ((quad * 2 + 0) ^ m)) * 4]);
        const float4 x1 = *reinterpret_cast<const float4*>(
            &Abuf[lr][(kc * 8 + ((quad * 2 + 1) ^ m)) * 4]);
        short8 af;
        af[0] = f2bf(x0.x); af[1] = f2bf(x0.y); af[2] = f2bf(x0.z); af[3] = f2bf(x0.w);
        af[4] = f2bf(x1.x); af[5] = f2bf(x1.y); af[6] = f2bf(x1.z); af[7] = f2bf(x1.w);

        const u16* bp = BgL + (size_t)kc * 4096;
        #pragma unroll
        for (int ct = 0; ct < 4; ct++) {
            short8 bf = *reinterpret_cast<const short8*>(bp + ct * 128);
            accg[ct] = __builtin_amdgcn_mfma_f32_16x16x32_bf16(af, bf, accg[ct], 0, 0, 0);
        }
    }

    __syncthreads();   // all phase-1 A reads done (WAR before overwrite)

    // ---- stage A(fin) into the same buffer ----
    {
        const float* src = finS + (size_t)(nodeBase + w * 8) * 256;
        #pragma unroll
        for (int i = 0; i < 8; i++)
            async16(src + i * 256 + ((lane ^ i) << 2), &Abuf[w * 8 + i][0]);
    }
    __syncthreads();   // vmcnt(0) drain publishes A(fin)

    // ---- phase 2: gate += fin @ Wg[256:512]; t = fin @ Wt. 8 MFMA/iter ----
    #pragma unroll 2
    for (int kc = 0; kc < 8; kc++) {
        const float4 x0 = *reinterpret_cast<const float4*>(
            &Abuf[lr][(kc * 8 + ((quad * 2 + 0) ^ m)) * 4]);
        const float4 x1 = *reinterpret_cast<const float4*>(
            &Abuf[lr][(kc * 8 + ((quad * 2 + 1) ^ m)) * 4]);
        short8 af;
        af[0] = f2bf(x0.x); af[1] = f2bf(x0.y); af[2] = f2bf(x0.z); af[3] = f2bf(x0.w);
        af[4] = f2bf(x1.x); af[5] = f2bf(x1.y); af[6] = f2bf(x1.z); af[7] = f2bf(x1.w);

        const u16* bpg = BgL + (size_t)(kc + 8) * 4096;
        const u16* bpt = BtL + (size_t)kc * 4096;
        #pragma unroll
        for (int ct = 0; ct < 4; ct++) {
            short8 bf = *reinterpret_cast<const short8*>(bpg + ct * 128);
            accg[ct] = __builtin_amdgcn_mfma_f32_16x16x32_bf16(af, bf, accg[ct], 0, 0, 0);
            short8 bt2 = *reinterpret_cast<const short8*>(bpt + ct * 128);
            acct[ct] = __builtin_amdgcn_mfma_f32_16x16x32_bf16(af, bt2, acct[ct], 0, 0, 0);
        }
    }

    // ---- epilogue: fuse + segment-sum from registers ----
    // C/D layout: col = colBase + ct*16 + l15, row (within wave tile) = quad*4 + i.
    const int gFirst = __shfl(myg, 0);    // lane 0 holds row r*16+0
    const int gLast  = __shfl(myg, 15);   // lane 15 holds row r*16+15
    const int colBase = c * 64;

    if (gFirst == gLast) {
        // fast path: whole 16-row wave tile in one graph
        #pragma unroll
        for (int ct = 0; ct < 4; ct++) {
            const int col = colBase + ct * 16 + l15;
            const float bgv = bg[col];
            const float btv = bt[col];
            float s = 0.f;
            #pragma unroll
            for (int i = 0; i < 4; i++) {
                float g = accg[ct][i] + bgv;
                float t = acct[ct][i] + btv;
                s += t / (1.0f + __expf(-g));
            }
            s += __shfl_xor(s, 16);   // sum across quads (rows)
            s += __shfl_xor(s, 32);
            if (ct == quad)           // 1 atomic per column per wave
                atomicAdd(&readout[gFirst * 128 + col], s);
        }
    } else {
        // slow path (~8% of waves at BM=32): per-lane sorted-run flush, 4 rows
        float s[4];
        #pragma unroll
        for (int ct = 0; ct < 4; ct++) s[ct] = 0.f;
        int curg = __shfl(myg, quad * 4);
        #pragma unroll
        for (int i = 0; i < 4; i++) {
            int g = __shfl(myg, quad * 4 + i);
            if (g != curg) {
                #pragma unroll
                for (int ct = 0; ct < 4; ct++) {
                    atomicAdd(&readout[curg * 128 + colBase + ct * 16 + l15], s[ct]);
                    s[ct] = 0.f;
                }
                curg = g;
            }
            #pragma unroll
            for (int ct = 0; ct < 4; ct++) {
                float gg = accg[ct][i] + bg[colBase + ct * 16 + l15];
                float tt = acct[ct][i] + bt[colBase + ct * 16 + l15];
                s[ct] += tt / (1.0f + __expf(-gg));
            }
        }
        #pragma unroll
        for (int ct = 0; ct < 4; ct++)
            atomicAdd(&readout[curg * 128 + colBase + ct * 16 + l15], s[ct]);
    }
}

// ---------------------------------------------------------------------------
// K2: BatchNorm column stats over the 1024-row batch (biased variance),
// folded into scale/shift: y = x*scale[c] + shift[c].
// ---------------------------------------------------------------------------
__global__ __launch_bounds__(256) void k2_stats(
    const float* __restrict__ readout, const float* __restrict__ aux,
    const float* __restrict__ gamma, const float* __restrict__ beta,
    float* __restrict__ scale, float* __restrict__ shift)
{
    const int col = blockIdx.x;     // 0..159
    const int tid = threadIdx.x;
    float s = 0.f, q = 0.f;
    for (int g = tid; g < 1024; g += 256) {
        float v = (col < 128) ? readout[g * 128 + col] : aux[g * 32 + (col - 128)];
        s += v; q += v * v;
    }
    #pragma unroll
    for (int off = 32; off > 0; off >>= 1) {
        s += __shfl_down(s, off);
        q += __shfl_down(q, off);
    }
    __shared__ float ps[4], pq[4];
    if ((tid & 63) == 0) { ps[tid >> 6] = s; pq[tid >> 6] = q; }
    __syncthreads();
    if (tid == 0) {
        float S = ps[0] + ps[1] + ps[2] + ps[3];
        float Q = pq[0] + pq[1] + pq[2] + pq[3];
        float mean = S * (1.0f / 1024.0f);
        float var  = Q * (1.0f / 1024.0f) - mean * mean;
        float rstd = rsqrtf(var + 1e-5f);
        float sc   = gamma[col] * rstd;
        scale[col] = sc;
        shift[col] = beta[col] - mean * sc;
    }
}

// ---------------------------------------------------------------------------
// K3a: hidden = relu(norm @ W1 + b1), BN fold applied inside the k-loop so the
// activations are RAW global rows (wave-uniform addresses -> scalar loads).
// ---------------------------------------------------------------------------
__global__ __launch_bounds__(256) void k3a_hidden(
    const float* __restrict__ readout, const float* __restrict__ aux,
    const float* __restrict__ scale, const float* __restrict__ shift,
    const float* __restrict__ W1, const float* __restrict__ b1,
    float* __restrict__ hidden)
{
    const int g0  = blockIdx.x * 4;   // 256 blocks
    const int tid = threadIdx.x;
    const float* r0 = readout + (size_t)g0 * 128;
    const float* a0 = aux     + (size_t)g0 * 32;

    #pragma unroll
    for (int jj = 0; jj < 2; jj++) {
        const int j = tid + jj * 256;
        float acc0 = 0.f, acc1 = 0.f, acc2 = 0.f, acc3 = 0.f, accS = 0.f;
        for (int k = 0; k < 128; k++) {
            float wv = W1[k * 512 + j];
            accS += shift[k] * wv;
            float wsv = scale[k] * wv;
            acc0 += r0[k]       * wsv;
            acc1 += r0[128 + k] * wsv;
            acc2 += r0[256 + k] * wsv;
            acc3 += r0[384 + k] * wsv;
        }
        for (int k = 0; k < 32; k++) {
            float wv = W1[(128 + k) * 512 + j];
            accS += shift[128 + k] * wv;
            float wsv = scale[128 + k] * wv;
            acc0 += a0[k]      * wsv;
            acc1 += a0[32 + k] * wsv;
            acc2 += a0[64 + k] * wsv;
            acc3 += a0[96 + k] * wsv;
        }
        float bb = b1[j] + accS;
        hidden[(size_t)(g0 + 0) * 512 + j] = fmaxf(acc0 + bb, 0.f);
        hidden[(size_t)(g0 + 1) * 512 + j] = fmaxf(acc1 + bb, 0.f);
        hidden[(size_t)(g0 + 2) * 512 + j] = fmaxf(acc2 + bb, 0.f);
        hidden[(size_t)(g0 + 3) * 512 + j] = fmaxf(acc3 + bb, 0.f);
    }
}

// ---------------------------------------------------------------------------
// K3b: logits = hidden @ W2 + b2. Same uniform-broadcast trick on hidden rows.
// ---------------------------------------------------------------------------
__global__ __launch_bounds__(256) void k3b_logits(
    const float* __restrict__ hidden, const float* __restrict__ W2,
    const float* __restrict__ b2, float* __restrict__ out)
{
    const int g0  = blockIdx.x * 4;   // 256 blocks
    const int tid = threadIdx.x;
    const int j   = tid & 127;
    const int rh  = tid >> 7;         // rows rh*2, rh*2+1
    const float* h0 = hidden + (size_t)(g0 + rh * 2) * 512;
    float acc0 = 0.f, acc1 = 0.f;
    for (int k = 0; k < 512; k++) {
        float wv = W2[k * 128 + j];
        acc0 += h0[k]       * wv;
        acc1 += h0[512 + k] * wv;
    }
    float bb = b2[j];
    out[(size_t)(g0 + rh * 2 + 0) * 128 + j] = acc0 + bb;
    out[(size_t)(g0 + rh * 2 + 1) * 128 + j] = acc1 + bb;
}

// ---------------------------------------------------------------------------
extern "C" void kernel_launch(void* const* d_in, const int* in_sizes, int n_in,
                              void* d_out, int out_size, void* d_ws, size_t ws_size,
                              hipStream_t stream)
{
    const float* initS = (const float*)d_in[0];   // [400000,256]
    const float* finS  = (const float*)d_in[1];   // [400000,256]
    const float* aux   = (const float*)d_in[2];   // [1024,32]
    const int*   gid   = (const int*)d_in[3];     // [400000] sorted
    // d_in[4] = num_graphs scalar (1024), unused
    const float* Wg    = (const float*)d_in[5];   // [512,128]
    const float* bg    = (const float*)d_in[6];   // [128]
    const float* Wt    = (const float*)d_in[7];   // [256,128]
    const float* bt    = (const float*)d_in[8];   // [128]
    const float* gamma = (const float*)d_in[9];   // [160]
    const float* beta  = (const float*)d_in[10];  // [160]
    const float* W1    = (const float*)d_in[11];  // [160,512]
    const float* b1    = (const float*)d_in[12];  // [512]
    const float* W2    = (const float*)d_in[13];  // [512,128]
    const float* b2    = (const float*)d_in[14];  // [128]
    float* out = (float*)d_out;                   // [1024,128]

    char* ws = (char*)d_ws;
    u16*   Bp      = (u16*)(ws + 0);              // 192 KB packed bf16 weights
    float* readout = (float*)(ws + 262144);       // 512 KB  [1024,128]
    float* scale   = (float*)(ws + 786432);       // 640 B
    float* shift   = (float*)(ws + 787456);       // 640 B
    float* hidden  = (float*)(ws + 1048576);      // 2 MB    [1024,512]

    k0_build  <<<96, 256, 0, stream>>>(Wg, Wt, Bp);
    hipMemsetAsync(readout, 0, 1024 * 128 * sizeof(float), stream);
    k1_gemm   <<<NNODES / BM, 256, 0, stream>>>(initS, finS, gid, Bp, bg, bt, readout);
    k2_stats  <<<160, 256, 0, stream>>>(readout, aux, gamma, beta, scale, shift);
    k3a_hidden<<<256, 256, 0, stream>>>(readout, aux, scale, shift, W1, b1, hidden);
    k3b_logits<<<256, 256, 0, stream>>>(hidden, W2, b2, out);
}